// Round 10
// baseline (200.261 us; speedup 1.0000x reference)
//
#include <hip/hip_runtime.h>

#define GLOBAL_AS __attribute__((address_space(1)))
#define LDS_AS    __attribute__((address_space(3)))

typedef int   i32x4  __attribute__((ext_vector_type(4)));
typedef int   i32x8  __attribute__((ext_vector_type(8)));
typedef float f32x4  __attribute__((ext_vector_type(4)));

// ---------- kernel 1: fused L2 normalize -> fp8 e4m3 of (x * 32 / ||row||) ----------
__global__ __launch_bounds__(256) void l2norm_fp8_kernel(const float* __restrict__ audio,
                                                         const float* __restrict__ visual,
                                                         unsigned char* __restrict__ out) {
    const int gw = blockIdx.x * 4 + (threadIdx.x >> 6);  // global row 0..24575
    const int l  = threadIdx.x & 63;
    const float* src = (gw < 16384) ? (audio + (size_t)gw * 768)
                                    : (visual + ((size_t)gw - 16384) * 768);
    const float4* p = (const float4*)src;
    float4 a = p[l], b = p[l + 64], c = p[l + 128];
    float ss = a.x * a.x + a.y * a.y + a.z * a.z + a.w * a.w
             + b.x * b.x + b.y * b.y + b.z * b.z + b.w * b.w
             + c.x * c.x + c.y * c.y + c.z * c.z + c.w * c.w;
#pragma unroll
    for (int m = 1; m < 64; m <<= 1) ss += __shfl_xor(ss, m, 64);
    const float s = 32.0f / fmaxf(sqrtf(ss), 1e-12f);
    unsigned int* o = (unsigned int*)(out + (size_t)gw * 768);
    int d0 = __builtin_amdgcn_cvt_pk_fp8_f32(a.x * s, a.y * s, 0, false);
    d0     = __builtin_amdgcn_cvt_pk_fp8_f32(a.z * s, a.w * s, d0, true);
    int d1 = __builtin_amdgcn_cvt_pk_fp8_f32(b.x * s, b.y * s, 0, false);
    d1     = __builtin_amdgcn_cvt_pk_fp8_f32(b.z * s, b.w * s, d1, true);
    int d2 = __builtin_amdgcn_cvt_pk_fp8_f32(c.x * s, c.y * s, 0, false);
    d2     = __builtin_amdgcn_cvt_pk_fp8_f32(c.z * s, c.w * s, d2, true);
    o[l] = (unsigned int)d0; o[l + 64] = (unsigned int)d1; o[l + 128] = (unsigned int)d2;
}

// ---------- kernel 2: 128x128-tile fp8 GEMM (mfma_scale 16x16x128), fused row-max ---
// m97/m148-style: 256 threads (4 waves, 2wm x 2wn), wave tile 64x64, single-buffered
// 32 KiB LDS, 2 barriers per K-tile, compiler-managed waits, ~3 blocks/CU.
// K = 768 = 6 x BK(128).
//
// FRAG-SLOT LDS layout (R7-proven 0-conflict): slot16 = fi<<7 | h<<6 | lane, i.e.
//   byte = fi*2048 + h*1024 + lane*16, holding element
//   (row = fi*16 + (lane&15), kb = (lane>>4)*32 + h*16),  fi = wm*4+mi (A) / wn*4+ni (B).
// Every ds_read_b128 is base + lane*16 (lane-linear -> 0 bank conflicts); staging
// dest is linear tid*16; the permutation lives in the per-lane GLOBAL source:
//   chunk q dest o = q*4096 + tid*16  ->  row = q*32 + (tid>>7)*16 + (tid&15),
//   kb = ((tid>>4)&3)*32 + ((tid>>6)&1)*16   (chunk step = +32 rows = +24576 B).
//
// L2-LOCALITY block order: bx = (x=XCD 0..7) | idx*8, idx -> (g,r,c):
//   rowBlk = x*16 + r, colBlk = g*16 + c. Per-XCD working set per group =
//   16 A-tiles (1.57 MB) + 16 V-tiles (1.57 MB) = 3.1 MB < 4 MB L2 -> V fetched
//   ~once per group instead of once per rowBlk (R9: FETCH 382 MB for 19 MB data).
// NOTE: keep launch_bounds min-waves at 3 (R5 lesson: over-capping VGPRs spills
// the accumulator -> 8 GB scratch traffic, 5.5x slower).

__device__ __forceinline__ i32x8 rd_frag(const char* p) {
    i32x4 lo = *(const i32x4*)(p);           // h=0 slot: kb = lg*32 .. +15
    i32x4 hi = *(const i32x4*)(p + 1024);    // h=1 slot: kb = lg*32+16 .. +31
    return __builtin_shufflevector(lo, hi, 0, 1, 2, 3, 4, 5, 6, 7);
}

__global__ __launch_bounds__(256, 3) void gemm_max_kernel(
    const unsigned char* __restrict__ A, const unsigned char* __restrict__ V,
    float* __restrict__ rowhalf) {
    __shared__ __align__(1024) char smem[32768];

    const int tid = threadIdx.x;
    const int l   = tid & 63;
    const int wid = tid >> 6;
    const int wm  = wid >> 1;      // 0..1 : 64-row half of A tile
    const int wn  = wid & 1;       // 0..1 : 64-col half of B tile
    const int lr  = l & 15;        // row/col within 16
    const int lg  = l >> 4;        // k-group 0..3 (32 B each)

    // block mapping: XCD-chunked + L2-friendly (colGroup, rowBlk, colBlk) order
    const int bx  = blockIdx.x;       // 8192 blocks
    const int x   = bx & 7;           // XCD
    const int idx = bx >> 3;          // 0..1023 within XCD
    const int g   = idx >> 8;         // colGroup 0..3
    const int r   = (idx >> 4) & 15;  // rowBlk within XCD's 16
    const int c   = idx & 15;         // colBlk within group
    const int rowBlk = x * 16 + r;    // 0..127
    const int colBlk = g * 16 + c;    // 0..63  (clip = colBlk>>1)
    const size_t aRow0 = (size_t)rowBlk * 128;
    const size_t vRow0 = (size_t)colBlk * 128;

    // staging source (frag-slot inverse mapping; see header comment)
    const int rowT = ((tid >> 7) << 4) + (tid & 15);                 // 0..31
    const int kbT  = ((tid >> 4) & 3) * 32 + ((tid >> 6) & 1) * 16;  // 0..112
    const unsigned char* aStage = A + (aRow0 + rowT) * 768 + kbT;
    const unsigned char* vStage = V + (vRow0 + rowT) * 768 + kbT;

    // reader bases: lane-linear; + mi*2048 / + ni*2048 per fragment
    const int aBase = wm * 8192 + l * 16;
    const int bBase = 16384 + wn * 8192 + l * 16;

    f32x4 acc[4][4];
#pragma unroll
    for (int i = 0; i < 4; ++i)
#pragma unroll
        for (int j = 0; j < 4; ++j) {
            acc[i][j][0] = 0.0f; acc[i][j][1] = 0.0f;
            acc[i][j][2] = 0.0f; acc[i][j][3] = 0.0f;
        }

#pragma unroll 1
    for (int kt = 0; kt < 6; ++kt) {
        __syncthreads();  // previous tile's reads done before overwrite
        const size_t ko = (size_t)kt * 128;
#pragma unroll
        for (int q = 0; q < 4; ++q) {
            __builtin_amdgcn_global_load_lds(
                (GLOBAL_AS void*)(aStage + ko + (size_t)q * 24576),
                (LDS_AS void*)(smem + q * 4096 + tid * 16), 16, 0, 0);
        }
#pragma unroll
        for (int q = 0; q < 4; ++q) {
            __builtin_amdgcn_global_load_lds(
                (GLOBAL_AS void*)(vStage + ko + (size_t)q * 24576),
                (LDS_AS void*)(smem + 16384 + q * 4096 + tid * 16), 16, 0, 0);
        }
        __syncthreads();  // compiler drains vmcnt(0) before barrier -> tile ready

        i32x8 fb[4];
#pragma unroll
        for (int ni = 0; ni < 4; ++ni) fb[ni] = rd_frag(smem + bBase + ni * 2048);
#pragma unroll
        for (int mi = 0; mi < 4; ++mi) {
            const i32x8 fav = rd_frag(smem + aBase + mi * 2048);
#pragma unroll
            for (int ni = 0; ni < 4; ++ni)
                acc[mi][ni] = __builtin_amdgcn_mfma_scale_f32_16x16x128_f8f6f4(
                    fav, fb[ni], acc[mi][ni], 0, 0, 0, 0x7F7F7F7F, 0, 0x7F7F7F7F);
        }
    }

    // epilogue: fused row-max over this block's 128 visual cols.
    // C/D layout (16x16): col = lane&15, row = (lane>>4)*4 + reg  (m89; shape-
    // determined for f8f6f4-scaled too)
    __syncthreads();
    float* pm = (float*)smem;  // [128 rows][2 wn]
#pragma unroll
    for (int mi = 0; mi < 4; ++mi) {
#pragma unroll
        for (int j = 0; j < 4; ++j) {
            float m = fmaxf(fmaxf(acc[mi][0][j], acc[mi][1][j]),
                            fmaxf(acc[mi][2][j], acc[mi][3][j]));
            m = fmaxf(m, __shfl_xor(m, 1, 64));
            m = fmaxf(m, __shfl_xor(m, 2, 64));
            m = fmaxf(m, __shfl_xor(m, 4, 64));
            m = fmaxf(m, __shfl_xor(m, 8, 64));
            if (lr == 0) {
                const int row = wm * 64 + mi * 16 + lg * 4 + j;
                pm[row * 2 + wn] = m;
            }
        }
    }
    __syncthreads();
    if (tid < 128) {
        float m = fmaxf(pm[tid * 2], pm[tid * 2 + 1]);
        rowhalf[(size_t)colBlk * 16384 + aRow0 + tid] = m;
    }
}

// ---------- kernel 3: combine halves (max) + mean over 512 rows -> clip_sims ----------
// folds 1/temp (x10), 1/512 mean, and 1/1024 fp8 pre-scale compensation (32*32).
__global__ __launch_bounds__(256) void reduce_mean_kernel(const float* __restrict__ rh,
                                                          float* __restrict__ clip) {
    const int b = blockIdx.x >> 5;
    const int c = blockIdx.x & 31;
    const int t = threadIdx.x;
    const float* p0 = rh + (size_t)(c * 2) * 16384 + (size_t)b * 512;
    const float* p1 = p0 + 16384;
    float s = fmaxf(p0[t], p1[t]) + fmaxf(p0[t + 256], p1[t + 256]);
#pragma unroll
    for (int m = 1; m < 64; m <<= 1) s += __shfl_xor(s, m, 64);
    __shared__ float wsum[4];
    if ((t & 63) == 0) wsum[t >> 6] = s;
    __syncthreads();
    if (t == 0)
        clip[b * 32 + c] = (wsum[0] + wsum[1] + wsum[2] + wsum[3]) * (1.0f / (51.2f * 1024.0f));
}

// ---------- kernel 4: log-softmax both ways on 32x32 + scalar loss ----------
__global__ __launch_bounds__(1024) void finalize_kernel(const float* __restrict__ clip,
                                                        float* __restrict__ out) {
    __shared__ float cs[32][33];
    __shared__ float rlse[32], clse[32];
    const int t = threadIdx.x;
    const int b = t >> 5, c = t & 31;
    cs[b][c] = clip[b * 32 + c];
    __syncthreads();
    if (t < 32) {
        float mx = -1e30f;
        for (int j = 0; j < 32; ++j) mx = fmaxf(mx, cs[t][j]);
        float s = 0.0f;
        for (int j = 0; j < 32; ++j) s += expf(cs[t][j] - mx);
        rlse[t] = mx + logf(s);
    } else if (t < 64) {
        const int cc = t - 32;
        float mx = -1e30f;
        for (int j = 0; j < 32; ++j) mx = fmaxf(mx, cs[j][cc]);
        float s = 0.0f;
        for (int j = 0; j < 32; ++j) s += expf(cs[j][cc] - mx);
        clse[cc] = mx + logf(s);
    }
    __syncthreads();
    if (t == 0) {
        float L = 0.0f;
        for (int i = 0; i < 32; ++i)
            L += -0.5f * (2.0f * cs[i][i] - rlse[i] - clse[i]);
        out[0] = L * (1.0f / 32.0f);
    }
}

extern "C" void kernel_launch(void* const* d_in, const int* in_sizes, int n_in,
                              void* d_out, int out_size, void* d_ws, size_t ws_size,
                              hipStream_t stream) {
    const float* audio  = (const float*)d_in[0];   // (32, 512, 768) f32
    const float* visual = (const float*)d_in[1];   // (32, 256, 768) f32

    unsigned char* aN = (unsigned char*)d_ws;                   // 16384*768 fp8
    unsigned char* vN = aN + (size_t)16384 * 768;               // 8192*768 fp8
    float* rowhalf = (float*)(vN + (size_t)8192 * 768);         // 64*16384 f32
    float* clip    = rowhalf + (size_t)64 * 16384;              // 1024 f32
    float* out     = (float*)d_out;

    l2norm_fp8_kernel<<<6144, 256, 0, stream>>>(audio, visual, aN);
    gemm_max_kernel<<<8192, 256, 0, stream>>>(aN, vN, rowhalf);
    reduce_mean_kernel<<<1024, 256, 0, stream>>>(rowhalf, clip);
    finalize_kernel<<<1, 1024, 0, stream>>>(clip, out);
}

// Round 11
// 200.060 us; speedup vs baseline: 1.0010x; 1.0010x over previous
//
#include <hip/hip_runtime.h>

#define GLOBAL_AS __attribute__((address_space(1)))
#define LDS_AS    __attribute__((address_space(3)))

typedef int   i32x4  __attribute__((ext_vector_type(4)));
typedef int   i32x8  __attribute__((ext_vector_type(8)));
typedef float f32x4  __attribute__((ext_vector_type(4)));

// ---------- kernel 1: fused L2 normalize -> fp8 e4m3 of (x * 32 / ||row||) ----------
__global__ __launch_bounds__(256) void l2norm_fp8_kernel(const float* __restrict__ audio,
                                                         const float* __restrict__ visual,
                                                         unsigned char* __restrict__ out) {
    const int gw = blockIdx.x * 4 + (threadIdx.x >> 6);  // global row 0..24575
    const int l  = threadIdx.x & 63;
    const float* src = (gw < 16384) ? (audio + (size_t)gw * 768)
                                    : (visual + ((size_t)gw - 16384) * 768);
    const float4* p = (const float4*)src;
    float4 a = p[l], b = p[l + 64], c = p[l + 128];
    float ss = a.x * a.x + a.y * a.y + a.z * a.z + a.w * a.w
             + b.x * b.x + b.y * b.y + b.z * b.z + b.w * b.w
             + c.x * c.x + c.y * c.y + c.z * c.z + c.w * c.w;
#pragma unroll
    for (int m = 1; m < 64; m <<= 1) ss += __shfl_xor(ss, m, 64);
    const float s = 32.0f / fmaxf(sqrtf(ss), 1e-12f);
    unsigned int* o = (unsigned int*)(out + (size_t)gw * 768);
    int d0 = __builtin_amdgcn_cvt_pk_fp8_f32(a.x * s, a.y * s, 0, false);
    d0     = __builtin_amdgcn_cvt_pk_fp8_f32(a.z * s, a.w * s, d0, true);
    int d1 = __builtin_amdgcn_cvt_pk_fp8_f32(b.x * s, b.y * s, 0, false);
    d1     = __builtin_amdgcn_cvt_pk_fp8_f32(b.z * s, b.w * s, d1, true);
    int d2 = __builtin_amdgcn_cvt_pk_fp8_f32(c.x * s, c.y * s, 0, false);
    d2     = __builtin_amdgcn_cvt_pk_fp8_f32(c.z * s, c.w * s, d2, true);
    o[l] = (unsigned int)d0; o[l + 64] = (unsigned int)d1; o[l + 128] = (unsigned int)d2;
}

// ---------- kernel 2: 128x128-tile fp8 GEMM (mfma_scale 16x16x128), fused row-max ---
// m97/m148-style: 256 threads (4 waves, 2wm x 2wn), wave tile 64x64, single-buffered
// 32 KiB LDS, 2 barriers per K-tile, compiler-managed waits, ~3+ blocks/CU.
// K = 768 = 6 x BK(128).
//
// FRAG-SLOT LDS layout, v2 (coalesced staging AND linear-ish reads):
//   granule s (byte 16*s) = fi*128 + h*64 + lane  holds global element
//   (row = fi*16 + (lane&15), kb = 16*(lane>>4) + 64*h),  fi = wm*4+mi / wn*4+ni.
// STAGING (linear dest tid*16): source row = ((tid>>7)<<4)+(tid&15) + 32q,
//   kb = ((tid>>4)&3)*16 + ((tid>>6)&1)*64. A wave's 64-granule run = 16 rows x
//   CONTIGUOUS 64 B -> 16 fully-utilized cache lines (R10's scatter = 32 half-used
//   lines was the 162->195us regression).
// READS: lane l, frag fi: chunk1 at fi*2048 + 512*(l>>4) + 16*(l&15), chunk2 at
//   +256. Four contiguous 16-lane granule runs; distinct-mod-8 per 8-lane group
//   -> expect R7/R10's zero-conflict behavior.
//
// L2-LOCALITY block order (R10-verified: FETCH 382->45 MB): bx = XCD | idx*8;
//   idx -> (g,r,c): rowBlk = x*16+r, colBlk = g*16+c; per-XCD group set = 3.1 MB < 4 MB L2.
// NOTE: keep launch_bounds min-waves at 3 (R5 lesson: over-capping VGPRs spills
// the accumulator -> 8 GB scratch traffic, 5.5x slower).

__device__ __forceinline__ i32x8 rd_frag(const char* p) {
    i32x4 lo = *(const i32x4*)(p);           // kb 32*lg .. +15
    i32x4 hi = *(const i32x4*)(p + 256);     // kb 32*lg+16 .. +31
    return __builtin_shufflevector(lo, hi, 0, 1, 2, 3, 4, 5, 6, 7);
}

__global__ __launch_bounds__(256, 3) void gemm_max_kernel(
    const unsigned char* __restrict__ A, const unsigned char* __restrict__ V,
    float* __restrict__ rowhalf) {
    __shared__ __align__(1024) char smem[32768];

    const int tid = threadIdx.x;
    const int l   = tid & 63;
    const int wid = tid >> 6;
    const int wm  = wid >> 1;      // 0..1 : 64-row half of A tile
    const int wn  = wid & 1;       // 0..1 : 64-col half of B tile
    const int lr  = l & 15;        // row/col within 16
    const int lg  = l >> 4;        // k-group 0..3 (32 B each)

    // block mapping: XCD-chunked + L2-friendly (colGroup, rowBlk, colBlk) order
    const int bx  = blockIdx.x;       // 8192 blocks
    const int x   = bx & 7;           // XCD
    const int idx = bx >> 3;          // 0..1023 within XCD
    const int g   = idx >> 8;         // colGroup 0..3
    const int r   = (idx >> 4) & 15;  // rowBlk within XCD's 16
    const int c   = idx & 15;         // colBlk within group
    const int rowBlk = x * 16 + r;    // 0..127
    const int colBlk = g * 16 + c;    // 0..63  (clip = colBlk>>1)
    const size_t aRow0 = (size_t)rowBlk * 128;
    const size_t vRow0 = (size_t)colBlk * 128;

    // staging source (frag-slot v2 inverse mapping; see header comment)
    const int rowT = ((tid >> 7) << 4) + (tid & 15);                 // 0..31
    const int kbT  = ((tid >> 4) & 3) * 16 + ((tid >> 6) & 1) * 64;  // 0..112
    const unsigned char* aStage = A + (aRow0 + rowT) * 768 + kbT;
    const unsigned char* vStage = V + (vRow0 + rowT) * 768 + kbT;

    // reader bases: + mi*2048 / + ni*2048 per fragment; second chunk at +256
    const int aBase = wm * 8192 + lg * 512 + lr * 16;
    const int bBase = 16384 + wn * 8192 + lg * 512 + lr * 16;

    f32x4 acc[4][4];
#pragma unroll
    for (int i = 0; i < 4; ++i)
#pragma unroll
        for (int j = 0; j < 4; ++j) {
            acc[i][j][0] = 0.0f; acc[i][j][1] = 0.0f;
            acc[i][j][2] = 0.0f; acc[i][j][3] = 0.0f;
        }

#pragma unroll 1
    for (int kt = 0; kt < 6; ++kt) {
        __syncthreads();  // previous tile's reads done before overwrite
        const size_t ko = (size_t)kt * 128;
#pragma unroll
        for (int q = 0; q < 4; ++q) {
            __builtin_amdgcn_global_load_lds(
                (GLOBAL_AS void*)(aStage + ko + (size_t)q * 24576),
                (LDS_AS void*)(smem + q * 4096 + tid * 16), 16, 0, 0);
        }
#pragma unroll
        for (int q = 0; q < 4; ++q) {
            __builtin_amdgcn_global_load_lds(
                (GLOBAL_AS void*)(vStage + ko + (size_t)q * 24576),
                (LDS_AS void*)(smem + 16384 + q * 4096 + tid * 16), 16, 0, 0);
        }
        __syncthreads();  // compiler drains vmcnt(0) before barrier -> tile ready

        i32x8 fb[4];
#pragma unroll
        for (int ni = 0; ni < 4; ++ni) fb[ni] = rd_frag(smem + bBase + ni * 2048);
#pragma unroll
        for (int mi = 0; mi < 4; ++mi) {
            const i32x8 fav = rd_frag(smem + aBase + mi * 2048);
#pragma unroll
            for (int ni = 0; ni < 4; ++ni)
                acc[mi][ni] = __builtin_amdgcn_mfma_scale_f32_16x16x128_f8f6f4(
                    fav, fb[ni], acc[mi][ni], 0, 0, 0, 0x7F7F7F7F, 0, 0x7F7F7F7F);
        }
    }

    // epilogue: fused row-max over this block's 128 visual cols.
    // C/D layout (16x16): col = lane&15, row = (lane>>4)*4 + reg  (m89; shape-
    // determined for f8f6f4-scaled too)
    __syncthreads();
    float* pm = (float*)smem;  // [128 rows][2 wn]
#pragma unroll
    for (int mi = 0; mi < 4; ++mi) {
#pragma unroll
        for (int j = 0; j < 4; ++j) {
            float m = fmaxf(fmaxf(acc[mi][0][j], acc[mi][1][j]),
                            fmaxf(acc[mi][2][j], acc[mi][3][j]));
            m = fmaxf(m, __shfl_xor(m, 1, 64));
            m = fmaxf(m, __shfl_xor(m, 2, 64));
            m = fmaxf(m, __shfl_xor(m, 4, 64));
            m = fmaxf(m, __shfl_xor(m, 8, 64));
            if (lr == 0) {
                const int row = wm * 64 + mi * 16 + lg * 4 + j;
                pm[row * 2 + wn] = m;
            }
        }
    }
    __syncthreads();
    if (tid < 128) {
        float m = fmaxf(pm[tid * 2], pm[tid * 2 + 1]);
        rowhalf[(size_t)colBlk * 16384 + aRow0 + tid] = m;
    }
}

// ---------- kernel 3: combine halves (max) + mean over 512 rows -> clip_sims ----------
// folds 1/temp (x10), 1/512 mean, and 1/1024 fp8 pre-scale compensation (32*32).
__global__ __launch_bounds__(256) void reduce_mean_kernel(const float* __restrict__ rh,
                                                          float* __restrict__ clip) {
    const int b = blockIdx.x >> 5;
    const int c = blockIdx.x & 31;
    const int t = threadIdx.x;
    const float* p0 = rh + (size_t)(c * 2) * 16384 + (size_t)b * 512;
    const float* p1 = p0 + 16384;
    float s = fmaxf(p0[t], p1[t]) + fmaxf(p0[t + 256], p1[t + 256]);
#pragma unroll
    for (int m = 1; m < 64; m <<= 1) s += __shfl_xor(s, m, 64);
    __shared__ float wsum[4];
    if ((t & 63) == 0) wsum[t >> 6] = s;
    __syncthreads();
    if (t == 0)
        clip[b * 32 + c] = (wsum[0] + wsum[1] + wsum[2] + wsum[3]) * (1.0f / (51.2f * 1024.0f));
}

// ---------- kernel 4: log-softmax both ways on 32x32 + scalar loss ----------
__global__ __launch_bounds__(1024) void finalize_kernel(const float* __restrict__ clip,
                                                        float* __restrict__ out) {
    __shared__ float cs[32][33];
    __shared__ float rlse[32], clse[32];
    const int t = threadIdx.x;
    const int b = t >> 5, c = t & 31;
    cs[b][c] = clip[b * 32 + c];
    __syncthreads();
    if (t < 32) {
        float mx = -1e30f;
        for (int j = 0; j < 32; ++j) mx = fmaxf(mx, cs[t][j]);
        float s = 0.0f;
        for (int j = 0; j < 32; ++j) s += expf(cs[t][j] - mx);
        rlse[t] = mx + logf(s);
    } else if (t < 64) {
        const int cc = t - 32;
        float mx = -1e30f;
        for (int j = 0; j < 32; ++j) mx = fmaxf(mx, cs[j][cc]);
        float s = 0.0f;
        for (int j = 0; j < 32; ++j) s += expf(cs[j][cc] - mx);
        clse[cc] = mx + logf(s);
    }
    __syncthreads();
    if (t == 0) {
        float L = 0.0f;
        for (int i = 0; i < 32; ++i)
            L += -0.5f * (2.0f * cs[i][i] - rlse[i] - clse[i]);
        out[0] = L * (1.0f / 32.0f);
    }
}

extern "C" void kernel_launch(void* const* d_in, const int* in_sizes, int n_in,
                              void* d_out, int out_size, void* d_ws, size_t ws_size,
                              hipStream_t stream) {
    const float* audio  = (const float*)d_in[0];   // (32, 512, 768) f32
    const float* visual = (const float*)d_in[1];   // (32, 256, 768) f32

    unsigned char* aN = (unsigned char*)d_ws;                   // 16384*768 fp8
    unsigned char* vN = aN + (size_t)16384 * 768;               // 8192*768 fp8
    float* rowhalf = (float*)(vN + (size_t)8192 * 768);         // 64*16384 f32
    float* clip    = rowhalf + (size_t)64 * 16384;              // 1024 f32
    float* out     = (float*)d_out;

    l2norm_fp8_kernel<<<6144, 256, 0, stream>>>(audio, visual, aN);
    gemm_max_kernel<<<8192, 256, 0, stream>>>(aN, vN, rowhalf);
    reduce_mean_kernel<<<1024, 256, 0, stream>>>(rowhalf, clip);
    finalize_kernel<<<1, 1024, 0, stream>>>(clip, out);
}